// Round 2
// baseline (9294.878 us; speedup 1.0000x reference)
//
#include <hip/hip_runtime.h>
#include <math.h>

#define TPB 256

// ---------------- workspace layout ----------------
// aux (fp32), float offsets within [0, 262144):
#define OFF_PN2   0          // 256   |protos_j|^2
#define OFF_GN2   256        // 256   |grid_j|^2
#define OFF_GATE  512        // 256   sigmoid(gate_logits)
#define OFF_TEMP  768        // 1
#define OFF_WEFF  1024       // 2560  W_eff[d][c] = sum_h clf_w[h*256+d][c]
#define OFF_PT    4096       // 65536 protosT[d][j]
#define OFF_GT    69632      // 65536 gridT[d][j]
// byte offsets of big regions:
//  A: h1 bf16 (4096*7200=58.98MB) then h4-chunk bf16 (2048*16384=64MB)
//  B: h2 bf16 (4096*4096=32MB)
//  Z: z0 fp32 (4MB)
#define OFF_A_BYTES   1048576ul
#define OFF_B_BYTES   (OFF_A_BYTES + 67108864ul)
#define OFF_Z0_BYTES  (OFF_B_BYTES + 33554432ul)
// total: ~105.9 MB

// ---------------- bf16 helpers ----------------
__device__ __forceinline__ float bf2f(ushort u) {
  return __uint_as_float(((unsigned)u) << 16);
}
__device__ __forceinline__ ushort f2bf(float f) {   // round-to-nearest-even
  unsigned x = __float_as_uint(f);
  return (ushort)((x + 0x7fffu + ((x >> 16) & 1u)) >> 16);
}
__device__ __forceinline__ unsigned pack2(float a, float b) {
  return (unsigned)f2bf(a) | ((unsigned)f2bf(b) << 16);
}

// ---------------- block reductions ----------------
__device__ __forceinline__ float block_sum(float v, float* red) {
  #pragma unroll
  for (int off = 32; off > 0; off >>= 1) v += __shfl_down(v, off, 64);
  int wid = threadIdx.x >> 6;
  __syncthreads();
  if ((threadIdx.x & 63) == 0) red[wid] = v;
  __syncthreads();
  return red[0] + red[1] + red[2] + red[3];
}
__device__ __forceinline__ float block_max(float v, float* red) {
  #pragma unroll
  for (int off = 32; off > 0; off >>= 1) v = fmaxf(v, __shfl_down(v, off, 64));
  int wid = threadIdx.x >> 6;
  __syncthreads();
  if ((threadIdx.x & 63) == 0) red[wid] = v;
  __syncthreads();
  return fmaxf(fmaxf(red[0], red[1]), fmaxf(red[2], red[3]));
}

// ---------------- setup ----------------
__global__ void __launch_bounds__(256) k_setup(const float* __restrict__ protos,
    const float* __restrict__ gridp, const float* __restrict__ gate_logits,
    const float* __restrict__ temp_raw, const float* __restrict__ clf_w,
    float* __restrict__ ws) {
  __shared__ float red[4];
  int b = blockIdx.x, t = threadIdx.x;
  float pv = protos[b*256 + t];
  float gv = gridp [b*256 + t];
  ws[OFF_PT + t*256 + b] = pv;
  ws[OFF_GT + t*256 + b] = gv;
  float sp = block_sum(pv*pv, red);
  float sg = block_sum(gv*gv, red);
  if (t == 0) {
    ws[OFF_PN2 + b] = sp;
    ws[OFF_GN2 + b] = sg;
    ws[OFF_GATE + b] = 1.f/(1.f + expf(-gate_logits[b]));
  }
  if (b == 0) {
    for (int i = t; i < 2560; i += TPB) {
      int d = i/10, c = i%10;
      ws[OFF_WEFF + i] = clf_w[d*10+c] + clf_w[(256+d)*10+c]
                       + clf_w[(512+d)*10+c] + clf_w[(768+d)*10+c];
    }
    if (t == 0) {
      float s = 1.f/(1.f + expf(-temp_raw[0]));
      ws[OFF_TEMP] = s*(1.f - 0.001f) + 0.001f;
    }
  }
}

// ---------------- conv1: 3x32x32 -> 32x15x15, k5 s2 p1, relu (out bf16) ----------------
__global__ void __launch_bounds__(256) k_conv1(const float* __restrict__ x,
    const float* __restrict__ w, const float* __restrict__ bias, ushort* __restrict__ h1) {
  __shared__ float xs[3072];
  __shared__ float wt[75*32];
  __shared__ float bs[32];
  int b = blockIdx.x, t = threadIdx.x;
  for (int i = t; i < 3072; i += TPB) xs[i] = x[(size_t)b*3072 + i];
  for (int i = t; i < 2400; i += TPB) { int oc = i/75, j = i%75; wt[j*32 + oc] = w[i]; }
  if (t < 32) bs[t] = bias[t];
  __syncthreads();
  if (t < 225) {
    int oy = t/15, ox = t%15;
    float acc[32];
    #pragma unroll
    for (int o = 0; o < 32; ++o) acc[o] = bs[o];
    for (int ic = 0; ic < 3; ++ic)
      for (int ky = 0; ky < 5; ++ky) {
        int iy = 2*oy - 1 + ky;
        if (iy < 0 || iy > 31) continue;
        for (int kx = 0; kx < 5; ++kx) {
          int ix = 2*ox - 1 + kx;
          if (ix < 0 || ix > 31) continue;
          float xv = xs[ic*1024 + iy*32 + ix];
          const float4* wp = (const float4*)&wt[(ic*25 + ky*5 + kx)*32];
          #pragma unroll
          for (int g = 0; g < 8; ++g) {
            float4 w4 = wp[g];
            acc[g*4+0] += xv*w4.x; acc[g*4+1] += xv*w4.y;
            acc[g*4+2] += xv*w4.z; acc[g*4+3] += xv*w4.w;
          }
        }
      }
    #pragma unroll
    for (int o = 0; o < 32; ++o) h1[(size_t)b*7200 + o*225 + t] = f2bf(fmaxf(acc[o], 0.f));
  }
}

// ---------------- conv2: 32x15x15 -> 64x8x8, k3 s2 p1, relu (bf16 in/out) ----------------
__global__ void __launch_bounds__(256) k_conv2(const ushort* __restrict__ h1,
    const float* __restrict__ w, const float* __restrict__ bias, ushort* __restrict__ h2) {
  __shared__ float xp[32*17*20];   // padded [ic][17][20] fp32, 43.5 KB
  __shared__ float wt[72*65];      // 18.7 KB
  int b = blockIdx.x, t = threadIdx.x;
  for (int i = t; i < 32*17*20; i += TPB) xp[i] = 0.f;
  __syncthreads();
  for (int i = t; i < 7200; i += TPB) {
    int ic = i/225, p = i%225, iy = p/15, ix = p%15;
    xp[ic*340 + (iy+1)*20 + (ix+1)] = bf2f(h1[(size_t)b*7200 + i]);
  }
  int py = t >> 5, og = t & 31;
  float acc[2][8];
  #pragma unroll
  for (int o = 0; o < 2; ++o) {
    float bv = bias[og + 32*o];
    #pragma unroll
    for (int px = 0; px < 8; ++px) acc[o][px] = bv;
  }
  for (int icc = 0; icc < 4; ++icc) {
    __syncthreads();
    for (int i = t; i < 8*9*64; i += TPB) {
      int oc = i/72, r = i%72;
      wt[r*65 + oc] = w[oc*288 + icc*72 + r];
    }
    __syncthreads();
    for (int icl = 0; icl < 8; ++icl) {
      int ic = icc*8 + icl;
      #pragma unroll
      for (int ky = 0; ky < 3; ++ky) {
        const float4* rp = (const float4*)&xp[ic*340 + (2*py + ky)*20];
        float rr[20];
        #pragma unroll
        for (int g = 0; g < 5; ++g) ((float4*)rr)[g] = rp[g];
        #pragma unroll
        for (int kx = 0; kx < 3; ++kx) {
          int rbase = (icl*9 + ky*3 + kx)*65 + og;
          float w0 = wt[rbase], w1v = wt[rbase + 32];
          #pragma unroll
          for (int px = 0; px < 8; ++px) {
            float xv = rr[2*px + kx];
            acc[0][px] += xv*w0; acc[1][px] += xv*w1v;
          }
        }
      }
    }
  }
  #pragma unroll
  for (int o = 0; o < 2; ++o) {
    int oc = og + 32*o;
    unsigned* dst = (unsigned*)&h2[(size_t)b*4096 + oc*64 + py*8];
    dst[0] = pack2(fmaxf(acc[o][0],0.f), fmaxf(acc[o][1],0.f));
    dst[1] = pack2(fmaxf(acc[o][2],0.f), fmaxf(acc[o][3],0.f));
    dst[2] = pack2(fmaxf(acc[o][4],0.f), fmaxf(acc[o][5],0.f));
    dst[3] = pack2(fmaxf(acc[o][6],0.f), fmaxf(acc[o][7],0.f));
  }
}

// ---------------- conv3+conv4 fused: 64x8x8 -> (h3 in LDS) -> 256x8x8 (bf16 out) ----------
// xp2: h2 padded bf16 [ic<64][10][12], interior rows 1..8 cols 1..8
// h3p: h3 padded bf16 [oc<128][10][12], interior rows 1..8 cols 2..9 (even starts for b32 packs)
// wt : weight chunk union, conv3 [36][129] / conv4 [18][257], fp32
__global__ void __launch_bounds__(256) k_conv34(const ushort* __restrict__ h2,
    const float* __restrict__ w3, const float* __restrict__ b3,
    const float* __restrict__ w4, const float* __restrict__ b4,
    ushort* __restrict__ h4c, int img_base) {
  __shared__ ushort xp2[7680];     // 15360 B
  __shared__ ushort h3p[15360];    // 30720 B
  __shared__ float  wt[4644];      // 18576 B   (total 64656 B < 64 KiB)
  int b = img_base + blockIdx.x, t = threadIdx.x;
  for (int i = t; i < 3840; i += TPB) ((unsigned*)xp2)[i] = 0u;
  for (int i = t; i < 7680; i += TPB) ((unsigned*)h3p)[i] = 0u;
  __syncthreads();
  for (int i = t; i < 4096; i += TPB) {
    int ic = i >> 6, p = i & 63;
    xp2[ic*120 + ((p>>3) + 1)*12 + (p&7) + 1] = h2[(size_t)b*4096 + i];
  }
  int py = t >> 5, og = t & 31;

  // ---- conv3: oc = og + 32*o, o<4 ----
  float acc3[4][8];
  #pragma unroll
  for (int o = 0; o < 4; ++o) {
    float bv = b3[og + 32*o];
    #pragma unroll
    for (int px = 0; px < 8; ++px) acc3[o][px] = bv;
  }
  for (int icc = 0; icc < 16; ++icc) {
    __syncthreads();
    for (int i = t; i < 4*9*128; i += TPB) {
      int oc = i/36, r = i%36;
      wt[r*129 + oc] = w3[oc*576 + icc*36 + r];
    }
    __syncthreads();
    for (int icl = 0; icl < 4; ++icl) {
      int ic = icc*4 + icl;
      #pragma unroll
      for (int ky = 0; ky < 3; ++ky) {
        const ushort4* rp = (const ushort4*)&xp2[ic*120 + (py + ky)*12];
        ushort4 u0 = rp[0], u1 = rp[1], u2 = rp[2];
        float rr[12] = { bf2f(u0.x),bf2f(u0.y),bf2f(u0.z),bf2f(u0.w),
                         bf2f(u1.x),bf2f(u1.y),bf2f(u1.z),bf2f(u1.w),
                         bf2f(u2.x),bf2f(u2.y),bf2f(u2.z),bf2f(u2.w) };
        #pragma unroll
        for (int kx = 0; kx < 3; ++kx) {
          int rbase = (icl*9 + ky*3 + kx)*129 + og;
          float w0 = wt[rbase], w1v = wt[rbase+32], w2v = wt[rbase+64], w3v = wt[rbase+96];
          #pragma unroll
          for (int px = 0; px < 8; ++px) {
            float xv = rr[px + kx];
            acc3[0][px] += xv*w0; acc3[1][px] += xv*w1v;
            acc3[2][px] += xv*w2v; acc3[3][px] += xv*w3v;
          }
        }
      }
    }
  }
  __syncthreads();   // conv3 wt reads done; xp2 dead
  // write h3 (relu) into h3p, interior cols 2..9
  #pragma unroll
  for (int o = 0; o < 4; ++o) {
    int oc = og + 32*o;
    int base = oc*120 + (py+1)*12 + 2;
    #pragma unroll
    for (int g = 0; g < 4; ++g)
      *(unsigned*)&h3p[base + 2*g] =
          pack2(fmaxf(acc3[o][2*g],0.f), fmaxf(acc3[o][2*g+1],0.f));
  }
  __syncthreads();

  // ---- conv4: oc = og + 32*o, o<8 ----
  float acc4[8][8];
  #pragma unroll
  for (int o = 0; o < 8; ++o) {
    float bv = b4[og + 32*o];
    #pragma unroll
    for (int px = 0; px < 8; ++px) acc4[o][px] = bv;
  }
  for (int icc = 0; icc < 64; ++icc) {   // 64 chunks x 2 ic
    __syncthreads();
    for (int i = t; i < 2*9*256; i += TPB) {
      int oc = i/18, r = i%18;
      wt[r*257 + oc] = w4[oc*1152 + icc*18 + r];
    }
    __syncthreads();
    #pragma unroll
    for (int icl = 0; icl < 2; ++icl) {
      int ic = icc*2 + icl;
      #pragma unroll
      for (int ky = 0; ky < 3; ++ky) {
        const ushort4* rp = (const ushort4*)&h3p[ic*120 + (py + ky)*12];
        ushort4 u0 = rp[0], u1 = rp[1], u2 = rp[2];
        float rr[12] = { bf2f(u0.x),bf2f(u0.y),bf2f(u0.z),bf2f(u0.w),
                         bf2f(u1.x),bf2f(u1.y),bf2f(u1.z),bf2f(u1.w),
                         bf2f(u2.x),bf2f(u2.y),bf2f(u2.z),bf2f(u2.w) };
        #pragma unroll
        for (int kx = 0; kx < 3; ++kx) {
          int rbase = (icl*9 + ky*3 + kx)*257 + og;
          float wv[8];
          #pragma unroll
          for (int o = 0; o < 8; ++o) wv[o] = wt[rbase + 32*o];
          #pragma unroll
          for (int px = 0; px < 8; ++px) {
            float xv = rr[px + kx + 1];   // interior at cols 2..9
            #pragma unroll
            for (int o = 0; o < 8; ++o) acc4[o][px] += xv*wv[o];
          }
        }
      }
    }
  }
  int bl = blockIdx.x;
  #pragma unroll
  for (int o = 0; o < 8; ++o) {
    int oc = og + 32*o;
    unsigned* dst = (unsigned*)&h4c[(size_t)bl*16384 + oc*64 + py*8];
    dst[0] = pack2(fmaxf(acc4[o][0],0.f), fmaxf(acc4[o][1],0.f));
    dst[1] = pack2(fmaxf(acc4[o][2],0.f), fmaxf(acc4[o][3],0.f));
    dst[2] = pack2(fmaxf(acc4[o][4],0.f), fmaxf(acc4[o][5],0.f));
    dst[3] = pack2(fmaxf(acc4[o][6],0.f), fmaxf(acc4[o][7],0.f));
  }
}

// ---------------- enc (per 2048-image chunk): z0 = h4c @ enc_w ----------------
__global__ void __launch_bounds__(256) k_enc(const ushort* __restrict__ h4c,
    const float* __restrict__ ew, float* __restrict__ z0, int img_base) {
  __shared__ float As[16*33];
  __shared__ float Bs[16*128];
  const int t = threadIdx.x;
  const int mb = blockIdx.x & 63, nb = blockIdx.x >> 6;  // 64 mtiles x 2 ntiles
  const int M0 = mb*32, N0 = nb*128;
  const int tn = t & 31, tm = t >> 5;
  float acc[4][4];
  #pragma unroll
  for (int i = 0; i < 4; ++i)
    #pragma unroll
    for (int j = 0; j < 4; ++j) acc[i][j] = 0.f;
  for (int kk = 0; kk < 1024; ++kk) {
    const int k0 = kk*16;
    __syncthreads();
    #pragma unroll
    for (int u = 0; u < 2; ++u) {
      int i = t + u*256, m = i >> 4, k = i & 15;
      As[k*33 + m] = bf2f(h4c[(size_t)(M0+m)*16384 + k0 + k]);
    }
    #pragma unroll
    for (int u = 0; u < 8; ++u) {
      int i = t + u*256, k = i >> 7, n = i & 127;
      Bs[k*128 + n] = ew[(size_t)(k0+k)*256 + N0 + n];
    }
    __syncthreads();
    #pragma unroll
    for (int k = 0; k < 16; ++k) {
      float a0 = As[k*33 + tm*4+0], a1 = As[k*33 + tm*4+1];
      float a2 = As[k*33 + tm*4+2], a3 = As[k*33 + tm*4+3];
      float4 bv = *(const float4*)&Bs[k*128 + tn*4];
      acc[0][0]+=a0*bv.x; acc[0][1]+=a0*bv.y; acc[0][2]+=a0*bv.z; acc[0][3]+=a0*bv.w;
      acc[1][0]+=a1*bv.x; acc[1][1]+=a1*bv.y; acc[1][2]+=a1*bv.z; acc[1][3]+=a1*bv.w;
      acc[2][0]+=a2*bv.x; acc[2][1]+=a2*bv.y; acc[2][2]+=a2*bv.z; acc[2][3]+=a2*bv.w;
      acc[3][0]+=a3*bv.x; acc[3][1]+=a3*bv.y; acc[3][2]+=a3*bv.z; acc[3][3]+=a3*bv.w;
    }
  }
  #pragma unroll
  for (int m = 0; m < 4; ++m)
    *(float4*)&z0[(size_t)(img_base + M0 + tm*4 + m)*256 + N0 + tn*4] =
        make_float4(acc[m][0], acc[m][1], acc[m][2], acc[m][3]);
}

// ---------------- post ----------------
__global__ void __launch_bounds__(256) k_post(const float* __restrict__ z0,
    const float* __restrict__ enc_b, const float* __restrict__ nfw,
    const float* __restrict__ nfb, const float* __restrict__ protos,
    const float* __restrict__ ws, const float* __restrict__ clf_b,
    float* __restrict__ out) {
  __shared__ float z0s[256], zs[256], wj[256], bls[256];
  __shared__ float red[4];
  int b = blockIdx.x, t = threadIdx.x;
  z0s[t] = z0[(size_t)b*256 + t] + enc_b[t];
  __syncthreads();
  float zv = nfb[t];
  for (int e = 0; e < 256; ++e) zv += z0s[e]*nfw[e*256 + t];
  zs[t] = zv;
  float z2 = block_sum(zv*zv, red);
  const float* pT = ws + OFF_PT;
  const float* gT = ws + OFF_GT;
  float dp = 0.f, dg = 0.f;
  for (int d = 0; d < 256; ++d) {
    float zd = zs[d];
    dp += zd*pT[d*256 + t];
    dg += zd*gT[d*256 + t];
  }
  float d2p = z2 + ws[OFF_PN2 + t] - 2.f*dp;
  float d2g = z2 + ws[OFF_GN2 + t] - 2.f*dg;
  float dtot = sqrtf(fmaxf(d2p, 0.f)) + sqrtf(fmaxf(d2g, 0.f));
  float l = -dtot / ws[OFF_TEMP];
  float m  = block_max(l, red);
  float e  = expf(l - m);
  float E  = block_sum(e, red);
  float w1 = (e/E)*ws[OFF_GATE + t];
  float W  = block_sum(w1, red);
  float wv = w1/(W + 1e-8f);
  wj[t] = wv;
  __syncthreads();
  float bl = 0.f;
  for (int j = 0; j < 256; ++j) bl += wj[j]*protos[j*256 + t];
  bls[t] = bl;
  __syncthreads();
  if (t < 10) {
    float s = clf_b[t];
    for (int d = 0; d < 256; ++d) s += bls[d]*ws[OFF_WEFF + d*10 + t];
    out[(size_t)b*10 + t] = s;
  }
}

extern "C" void kernel_launch(void* const* d_in, const int* in_sizes, int n_in,
                              void* d_out, int out_size, void* d_ws, size_t ws_size,
                              hipStream_t stream) {
  (void)in_sizes; (void)n_in; (void)out_size; (void)ws_size;
  const float* x      = (const float*)d_in[0];
  const float* c1w    = (const float*)d_in[2];
  const float* c1b    = (const float*)d_in[3];
  const float* c2w    = (const float*)d_in[4];
  const float* c2b    = (const float*)d_in[5];
  const float* c3w    = (const float*)d_in[6];
  const float* c3b    = (const float*)d_in[7];
  const float* c4w    = (const float*)d_in[8];
  const float* c4b    = (const float*)d_in[9];
  const float* encw   = (const float*)d_in[10];
  const float* encb   = (const float*)d_in[11];
  // d_in[12..17] dead: softmax over a single node == 1 exactly
  const float* clfw   = (const float*)d_in[18];
  const float* clfb   = (const float*)d_in[19];
  const float* nfw    = (const float*)d_in[20];
  const float* nfb    = (const float*)d_in[21];
  const float* protos = (const float*)d_in[22];
  const float* gridp  = (const float*)d_in[23];
  const float* traw   = (const float*)d_in[24];
  const float* gatel  = (const float*)d_in[25];

  float*  ws  = (float*)d_ws;
  ushort* h1  = (ushort*)((char*)d_ws + OFF_A_BYTES);
  ushort* h4c = (ushort*)((char*)d_ws + OFF_A_BYTES);   // reuses h1 region (h1 dead)
  ushort* h2  = (ushort*)((char*)d_ws + OFF_B_BYTES);
  float*  z0  = (float*) ((char*)d_ws + OFF_Z0_BYTES);
  float*  out = (float*)d_out;

  hipLaunchKernelGGL(k_setup, dim3(256),  dim3(TPB), 0, stream, protos, gridp, gatel, traw, clfw, ws);
  hipLaunchKernelGGL(k_conv1, dim3(4096), dim3(TPB), 0, stream, x,  c1w, c1b, h1);
  hipLaunchKernelGGL(k_conv2, dim3(4096), dim3(TPB), 0, stream, h1, c2w, c2b, h2);
  for (int c = 0; c < 2; ++c) {
    hipLaunchKernelGGL(k_conv34, dim3(2048), dim3(TPB), 0, stream,
                       h2, c3w, c3b, c4w, c4b, h4c, c*2048);
    hipLaunchKernelGGL(k_enc, dim3(128), dim3(TPB), 0, stream, h4c, encw, z0, c*2048);
  }
  hipLaunchKernelGGL(k_post, dim3(4096), dim3(TPB), 0, stream, z0, encb, nfw, nfb, protos, ws, clfb, out);
}

// Round 3
// 4344.086 us; speedup vs baseline: 2.1397x; 2.1397x over previous
//
#include <hip/hip_runtime.h>
#include <math.h>

#define TPB 256

typedef __attribute__((ext_vector_type(8))) short bf16x8;
typedef __attribute__((ext_vector_type(4))) float f32x4;

// ---------------- workspace layout ----------------
// aux (fp32), float offsets:
#define OFF_PN2   0          // 256
#define OFF_GN2   256        // 256
#define OFF_GATE  512        // 256
#define OFF_TEMP  768        // 1
#define OFF_WEFF  1024       // 2560
#define OFF_PT    4096       // 65536 protosT[d][j]
#define OFF_GT    69632      // 65536 gridT[d][j]
// bf16 weight tables (byte offsets):
#define OFF_W3T_BYTES 786432ul    // 9*128*64  bf16 = 147456 B
#define OFF_W4T_BYTES 983040ul    // 9*256*128 bf16 = 589824 B
// big regions (byte offsets):
//  A: h1 bf16 (59 MB) then h4-chunk bf16 (64 MB);  B: h2 bf16 (32 MB);  Z: z0 fp32 (4 MB)
#define OFF_A_BYTES   2097152ul
#define OFF_B_BYTES   (OFF_A_BYTES + 67108864ul)
#define OFF_Z0_BYTES  (OFF_B_BYTES + 33554432ul)
// total ~102 MiB

// ---------------- bf16 helpers ----------------
__device__ __forceinline__ float bf2f(ushort u) {
  return __uint_as_float(((unsigned)u) << 16);
}
__device__ __forceinline__ ushort f2bf(float f) {   // RNE
  unsigned x = __float_as_uint(f);
  return (ushort)((x + 0x7fffu + ((x >> 16) & 1u)) >> 16);
}
__device__ __forceinline__ unsigned pack2(float a, float b) {
  return (unsigned)f2bf(a) | ((unsigned)f2bf(b) << 16);
}

// ---------------- block reductions ----------------
__device__ __forceinline__ float block_sum(float v, float* red) {
  #pragma unroll
  for (int off = 32; off > 0; off >>= 1) v += __shfl_down(v, off, 64);
  int wid = threadIdx.x >> 6;
  __syncthreads();
  if ((threadIdx.x & 63) == 0) red[wid] = v;
  __syncthreads();
  return red[0] + red[1] + red[2] + red[3];
}
__device__ __forceinline__ float block_max(float v, float* red) {
  #pragma unroll
  for (int off = 32; off > 0; off >>= 1) v = fmaxf(v, __shfl_down(v, off, 64));
  int wid = threadIdx.x >> 6;
  __syncthreads();
  if ((threadIdx.x & 63) == 0) red[wid] = v;
  __syncthreads();
  return fmaxf(fmaxf(red[0], red[1]), fmaxf(red[2], red[3]));
}

// ---------------- setup ----------------
__global__ void __launch_bounds__(256) k_setup(const float* __restrict__ protos,
    const float* __restrict__ gridp, const float* __restrict__ gate_logits,
    const float* __restrict__ temp_raw, const float* __restrict__ clf_w,
    float* __restrict__ ws) {
  __shared__ float red[4];
  int b = blockIdx.x, t = threadIdx.x;
  float pv = protos[b*256 + t];
  float gv = gridp [b*256 + t];
  ws[OFF_PT + t*256 + b] = pv;
  ws[OFF_GT + t*256 + b] = gv;
  float sp = block_sum(pv*pv, red);
  float sg = block_sum(gv*gv, red);
  if (t == 0) {
    ws[OFF_PN2 + b] = sp;
    ws[OFF_GN2 + b] = sg;
    ws[OFF_GATE + b] = 1.f/(1.f + expf(-gate_logits[b]));
  }
  if (b == 0) {
    for (int i = t; i < 2560; i += TPB) {
      int d = i/10, c = i%10;
      ws[OFF_WEFF + i] = clf_w[d*10+c] + clf_w[(256+d)*10+c]
                       + clf_w[(512+d)*10+c] + clf_w[(768+d)*10+c];
    }
    if (t == 0) {
      float s = 1.f/(1.f + expf(-temp_raw[0]));
      ws[OFF_TEMP] = s*(1.f - 0.001f) + 0.001f;
    }
  }
}

// ---------------- prep: bf16 per-tap weight tables ----------------
// w3t[tap][oc<128][ic<64], w4t[tap][oc<256][ic<128]
__global__ void __launch_bounds__(256) k_prep(const float* __restrict__ w3,
    const float* __restrict__ w4, ushort* __restrict__ w3t, ushort* __restrict__ w4t) {
  int idx = blockIdx.x*256 + threadIdx.x;          // grid covers 294912
  if (idx < 73728) {
    int tap = idx >> 13, r = idx & 8191, oc = r >> 6, ic = r & 63;
    w3t[idx] = f2bf(w3[oc*576 + ic*9 + tap]);
  }
  if (idx < 294912) {
    int tap = idx >> 15, r = idx & 32767, oc = r >> 7, ic = r & 127;
    w4t[idx] = f2bf(w4[oc*1152 + ic*9 + tap]);
  }
}

// ---------------- conv1: 3x32x32 -> 32x15x15, k5 s2 p1, relu (out bf16) ----------------
__global__ void __launch_bounds__(256) k_conv1(const float* __restrict__ x,
    const float* __restrict__ w, const float* __restrict__ bias, ushort* __restrict__ h1) {
  __shared__ float xs[3072];
  __shared__ float wt[75*32];
  __shared__ float bs[32];
  int b = blockIdx.x, t = threadIdx.x;
  for (int i = t; i < 3072; i += TPB) xs[i] = x[(size_t)b*3072 + i];
  for (int i = t; i < 2400; i += TPB) { int oc = i/75, j = i%75; wt[j*32 + oc] = w[i]; }
  if (t < 32) bs[t] = bias[t];
  __syncthreads();
  if (t < 225) {
    int oy = t/15, ox = t%15;
    float acc[32];
    #pragma unroll
    for (int o = 0; o < 32; ++o) acc[o] = bs[o];
    for (int ic = 0; ic < 3; ++ic)
      for (int ky = 0; ky < 5; ++ky) {
        int iy = 2*oy - 1 + ky;
        if (iy < 0 || iy > 31) continue;
        for (int kx = 0; kx < 5; ++kx) {
          int ix = 2*ox - 1 + kx;
          if (ix < 0 || ix > 31) continue;
          float xv = xs[ic*1024 + iy*32 + ix];
          const float4* wp = (const float4*)&wt[(ic*25 + ky*5 + kx)*32];
          #pragma unroll
          for (int g = 0; g < 8; ++g) {
            float4 w4 = wp[g];
            acc[g*4+0] += xv*w4.x; acc[g*4+1] += xv*w4.y;
            acc[g*4+2] += xv*w4.z; acc[g*4+3] += xv*w4.w;
          }
        }
      }
    #pragma unroll
    for (int o = 0; o < 32; ++o) h1[(size_t)b*7200 + o*225 + t] = f2bf(fmaxf(acc[o], 0.f));
  }
}

// ---------------- conv2: 32x15x15 -> 64x8x8, k3 s2 p1, relu, OUT CHANNEL-LAST ----------
// h2c[img][px<64][ic<64]
__global__ void __launch_bounds__(256) k_conv2(const ushort* __restrict__ h1,
    const float* __restrict__ w, const float* __restrict__ bias, ushort* __restrict__ h2c) {
  __shared__ float xp[32*17*20];   // 43.5 KB
  __shared__ float wt[72*65];      // 18.7 KB
  int b = blockIdx.x, t = threadIdx.x;
  for (int i = t; i < 32*17*20; i += TPB) xp[i] = 0.f;
  __syncthreads();
  for (int i = t; i < 7200; i += TPB) {
    int ic = i/225, p = i%225, iy = p/15, ix = p%15;
    xp[ic*340 + (iy+1)*20 + (ix+1)] = bf2f(h1[(size_t)b*7200 + i]);
  }
  int py = t >> 5, og = t & 31;
  float acc[2][8];
  #pragma unroll
  for (int o = 0; o < 2; ++o) {
    float bv = bias[og + 32*o];
    #pragma unroll
    for (int px = 0; px < 8; ++px) acc[o][px] = bv;
  }
  for (int icc = 0; icc < 4; ++icc) {
    __syncthreads();
    for (int i = t; i < 8*9*64; i += TPB) {
      int oc = i/72, r = i%72;
      wt[r*65 + oc] = w[oc*288 + icc*72 + r];
    }
    __syncthreads();
    for (int icl = 0; icl < 8; ++icl) {
      int ic = icc*8 + icl;
      #pragma unroll
      for (int ky = 0; ky < 3; ++ky) {
        const float4* rp = (const float4*)&xp[ic*340 + (2*py + ky)*20];
        float rr[20];
        #pragma unroll
        for (int g = 0; g < 5; ++g) ((float4*)rr)[g] = rp[g];
        #pragma unroll
        for (int kx = 0; kx < 3; ++kx) {
          int rbase = (icl*9 + ky*3 + kx)*65 + og;
          float w0 = wt[rbase], w1v = wt[rbase + 32];
          #pragma unroll
          for (int px = 0; px < 8; ++px) {
            float xv = rr[2*px + kx];
            acc[0][px] += xv*w0; acc[1][px] += xv*w1v;
          }
        }
      }
    }
  }
  #pragma unroll
  for (int o = 0; o < 2; ++o) {
    int oc = og + 32*o;
    #pragma unroll
    for (int px = 0; px < 8; ++px)
      h2c[(size_t)b*4096 + (py*8+px)*64 + oc] = f2bf(fmaxf(acc[o][px], 0.f));
  }
}

// ---------------- conv3+conv4 fused, MFMA implicit-GEMM ----------------
// xp : h2 channel-last padded [100 px][64+8]  (interior rows/cols 1..8)
// h3p: h3 channel-last padded [100 px][128+8]
// per-tap GEMM, B-frags straight from global (L2-resident weight tables)
__global__ void __launch_bounds__(256) k_conv34(const ushort* __restrict__ h2c,
    const float* __restrict__ b3, const float* __restrict__ b4,
    const ushort* __restrict__ w3t, const ushort* __restrict__ w4t,
    ushort* __restrict__ h4c, int img_base) {
  __shared__ ushort xp [100*72];    // 14400 B
  __shared__ ushort h3p[100*136];   // 27200 B
  int b = img_base + blockIdx.x, t = threadIdx.x;
  for (int i = t; i < 3600; i += TPB) ((unsigned*)xp)[i]  = 0u;
  for (int i = t; i < 6800; i += TPB) ((unsigned*)h3p)[i] = 0u;
  __syncthreads();
  #pragma unroll
  for (int u = 0; u < 2; ++u) {                 // stage h2 -> xp interior
    int i = t + u*256;                          // 512 x ushort8
    int px = i >> 3, icq = i & 7;
    int iy = px >> 3, ix = px & 7;
    bf16x8 v = *(const bf16x8*)&h2c[(size_t)b*4096 + (size_t)px*64 + icq*8];
    *(bf16x8*)&xp[((iy+1)*10 + ix + 1)*72 + icq*8] = v;
  }
  __syncthreads();

  const int lane = t & 63, wv = t >> 6;
  const int quad = lane >> 4, row16 = lane & 15;
  int aoy[4], aox[4];
  #pragma unroll
  for (int mt = 0; mt < 4; ++mt) {
    int px = mt*16 + row16;
    aoy[mt] = px >> 3; aox[mt] = px & 7;
  }

  // ---- conv3: wave -> oc [wv*32, wv*32+32), 2 N-tiles x 4 M-tiles ----
  f32x4 c3[4][2];
  #pragma unroll
  for (int mt = 0; mt < 4; ++mt) { c3[mt][0] = (f32x4)0.f; c3[mt][1] = (f32x4)0.f; }
  for (int ky = 0; ky < 3; ++ky)
    for (int kx = 0; kx < 3; ++kx) {
      int tap = ky*3 + kx;
      const ushort* wb = w3t + tap*8192 + (wv*32 + row16)*64 + quad*8;
      #pragma unroll
      for (int ks = 0; ks < 2; ++ks) {
        bf16x8 bf0 = *(const bf16x8*)(wb + ks*32);
        bf16x8 bf1 = *(const bf16x8*)(wb + 1024 + ks*32);      // +16 oc
        #pragma unroll
        for (int mt = 0; mt < 4; ++mt) {
          bf16x8 af = *(const bf16x8*)&xp[((aoy[mt]+ky)*10 + aox[mt]+kx)*72 + ks*32 + quad*8];
          c3[mt][0] = __builtin_amdgcn_mfma_f32_16x16x32_bf16(af, bf0, c3[mt][0], 0, 0, 0);
          c3[mt][1] = __builtin_amdgcn_mfma_f32_16x16x32_bf16(af, bf1, c3[mt][1], 0, 0, 0);
        }
      }
    }
  // bias+relu -> h3p interior (channel-last)
  #pragma unroll
  for (int nt = 0; nt < 2; ++nt) {
    int oc = wv*32 + nt*16 + row16;
    float bv = b3[oc];
    #pragma unroll
    for (int mt = 0; mt < 4; ++mt)
      #pragma unroll
      for (int r = 0; r < 4; ++r) {
        int px = mt*16 + quad*4 + r;
        int oy = px >> 3, ox = px & 7;
        h3p[((oy+1)*10 + ox + 1)*136 + oc] = f2bf(fmaxf(c3[mt][nt][r] + bv, 0.f));
      }
  }
  __syncthreads();

  // ---- conv4: wave -> oc [wv*64, wv*64+64), 4 N-tiles x 4 M-tiles ----
  f32x4 c4[4][4];
  #pragma unroll
  for (int mt = 0; mt < 4; ++mt)
    #pragma unroll
    for (int nt = 0; nt < 4; ++nt) c4[mt][nt] = (f32x4)0.f;
  for (int ky = 0; ky < 3; ++ky)
    for (int kx = 0; kx < 3; ++kx) {
      int tap = ky*3 + kx;
      const ushort* wb = w4t + tap*32768 + (wv*64 + row16)*128 + quad*8;
      #pragma unroll
      for (int ks = 0; ks < 4; ++ks) {
        bf16x8 bf[4];
        #pragma unroll
        for (int nt = 0; nt < 4; ++nt)
          bf[nt] = *(const bf16x8*)(wb + nt*2048 + ks*32);     // +16 oc = 2048 ushorts
        #pragma unroll
        for (int mt = 0; mt < 4; ++mt) {
          bf16x8 af = *(const bf16x8*)&h3p[((aoy[mt]+ky)*10 + aox[mt]+kx)*136 + ks*32 + quad*8];
          #pragma unroll
          for (int nt = 0; nt < 4; ++nt)
            c4[mt][nt] = __builtin_amdgcn_mfma_f32_16x16x32_bf16(af, bf[nt], c4[mt][nt], 0, 0, 0);
        }
      }
    }
  // bias+relu -> h4c in NCHW-flat order [oc*64+px] (keeps enc k-order)
  int bl = blockIdx.x;
  #pragma unroll
  for (int nt = 0; nt < 4; ++nt) {
    int oc = wv*64 + nt*16 + row16;
    float bv = b4[oc];
    #pragma unroll
    for (int mt = 0; mt < 4; ++mt) {
      int px0 = mt*16 + quad*4;
      uint2 dd;
      dd.x = pack2(fmaxf(c4[mt][nt][0] + bv, 0.f), fmaxf(c4[mt][nt][1] + bv, 0.f));
      dd.y = pack2(fmaxf(c4[mt][nt][2] + bv, 0.f), fmaxf(c4[mt][nt][3] + bv, 0.f));
      *(uint2*)&h4c[(size_t)bl*16384 + oc*64 + px0] = dd;
    }
  }
}

// ---------------- enc (per 2048-image chunk): z0 = h4c @ enc_w ----------------
__global__ void __launch_bounds__(256) k_enc(const ushort* __restrict__ h4c,
    const float* __restrict__ ew, float* __restrict__ z0, int img_base) {
  __shared__ float As[16*33];
  __shared__ float Bs[16*128];
  const int t = threadIdx.x;
  const int mb = blockIdx.x & 63, nb = blockIdx.x >> 6;
  const int M0 = mb*32, N0 = nb*128;
  const int tn = t & 31, tm = t >> 5;
  float acc[4][4];
  #pragma unroll
  for (int i = 0; i < 4; ++i)
    #pragma unroll
    for (int j = 0; j < 4; ++j) acc[i][j] = 0.f;
  for (int kk = 0; kk < 1024; ++kk) {
    const int k0 = kk*16;
    __syncthreads();
    #pragma unroll
    for (int u = 0; u < 2; ++u) {
      int i = t + u*256, m = i >> 4, k = i & 15;
      As[k*33 + m] = bf2f(h4c[(size_t)(M0+m)*16384 + k0 + k]);
    }
    #pragma unroll
    for (int u = 0; u < 8; ++u) {
      int i = t + u*256, k = i >> 7, n = i & 127;
      Bs[k*128 + n] = ew[(size_t)(k0+k)*256 + N0 + n];
    }
    __syncthreads();
    #pragma unroll
    for (int k = 0; k < 16; ++k) {
      float a0 = As[k*33 + tm*4+0], a1 = As[k*33 + tm*4+1];
      float a2 = As[k*33 + tm*4+2], a3 = As[k*33 + tm*4+3];
      float4 bv = *(const float4*)&Bs[k*128 + tn*4];
      acc[0][0]+=a0*bv.x; acc[0][1]+=a0*bv.y; acc[0][2]+=a0*bv.z; acc[0][3]+=a0*bv.w;
      acc[1][0]+=a1*bv.x; acc[1][1]+=a1*bv.y; acc[1][2]+=a1*bv.z; acc[1][3]+=a1*bv.w;
      acc[2][0]+=a2*bv.x; acc[2][1]+=a2*bv.y; acc[2][2]+=a2*bv.z; acc[2][3]+=a2*bv.w;
      acc[3][0]+=a3*bv.x; acc[3][1]+=a3*bv.y; acc[3][2]+=a3*bv.z; acc[3][3]+=a3*bv.w;
    }
  }
  #pragma unroll
  for (int m = 0; m < 4; ++m)
    *(float4*)&z0[(size_t)(img_base + M0 + tm*4 + m)*256 + N0 + tn*4] =
        make_float4(acc[m][0], acc[m][1], acc[m][2], acc[m][3]);
}

// ---------------- post ----------------
__global__ void __launch_bounds__(256) k_post(const float* __restrict__ z0,
    const float* __restrict__ enc_b, const float* __restrict__ nfw,
    const float* __restrict__ nfb, const float* __restrict__ protos,
    const float* __restrict__ ws, const float* __restrict__ clf_b,
    float* __restrict__ out) {
  __shared__ float z0s[256], zs[256], wj[256], bls[256];
  __shared__ float red[4];
  int b = blockIdx.x, t = threadIdx.x;
  z0s[t] = z0[(size_t)b*256 + t] + enc_b[t];
  __syncthreads();
  float zv = nfb[t];
  for (int e = 0; e < 256; ++e) zv += z0s[e]*nfw[e*256 + t];
  zs[t] = zv;
  float z2 = block_sum(zv*zv, red);
  const float* pT = ws + OFF_PT;
  const float* gT = ws + OFF_GT;
  float dp = 0.f, dg = 0.f;
  for (int d = 0; d < 256; ++d) {
    float zd = zs[d];
    dp += zd*pT[d*256 + t];
    dg += zd*gT[d*256 + t];
  }
  float d2p = z2 + ws[OFF_PN2 + t] - 2.f*dp;
  float d2g = z2 + ws[OFF_GN2 + t] - 2.f*dg;
  float dtot = sqrtf(fmaxf(d2p, 0.f)) + sqrtf(fmaxf(d2g, 0.f));
  float l = -dtot / ws[OFF_TEMP];
  float m  = block_max(l, red);
  float e  = expf(l - m);
  float E  = block_sum(e, red);
  float w1 = (e/E)*ws[OFF_GATE + t];
  float W  = block_sum(w1, red);
  float wv = w1/(W + 1e-8f);
  wj[t] = wv;
  __syncthreads();
  float bl = 0.f;
  for (int j = 0; j < 256; ++j) bl += wj[j]*protos[j*256 + t];
  bls[t] = bl;
  __syncthreads();
  if (t < 10) {
    float s = clf_b[t];
    for (int d = 0; d < 256; ++d) s += bls[d]*ws[OFF_WEFF + d*10 + t];
    out[(size_t)b*10 + t] = s;
  }
}

extern "C" void kernel_launch(void* const* d_in, const int* in_sizes, int n_in,
                              void* d_out, int out_size, void* d_ws, size_t ws_size,
                              hipStream_t stream) {
  (void)in_sizes; (void)n_in; (void)out_size; (void)ws_size;
  const float* x      = (const float*)d_in[0];
  const float* c1w    = (const float*)d_in[2];
  const float* c1b    = (const float*)d_in[3];
  const float* c2w    = (const float*)d_in[4];
  const float* c2b    = (const float*)d_in[5];
  const float* c3w    = (const float*)d_in[6];
  const float* c3b    = (const float*)d_in[7];
  const float* c4w    = (const float*)d_in[8];
  const float* c4b    = (const float*)d_in[9];
  const float* encw   = (const float*)d_in[10];
  const float* encb   = (const float*)d_in[11];
  // d_in[12..17] dead: softmax over a single node == 1 exactly
  const float* clfw   = (const float*)d_in[18];
  const float* clfb   = (const float*)d_in[19];
  const float* nfw    = (const float*)d_in[20];
  const float* nfb    = (const float*)d_in[21];
  const float* protos = (const float*)d_in[22];
  const float* gridp  = (const float*)d_in[23];
  const float* traw   = (const float*)d_in[24];
  const float* gatel  = (const float*)d_in[25];

  float*  ws  = (float*)d_ws;
  ushort* w3t = (ushort*)((char*)d_ws + OFF_W3T_BYTES);
  ushort* w4t = (ushort*)((char*)d_ws + OFF_W4T_BYTES);
  ushort* h1  = (ushort*)((char*)d_ws + OFF_A_BYTES);
  ushort* h4c = (ushort*)((char*)d_ws + OFF_A_BYTES);   // reuses h1 region
  ushort* h2c = (ushort*)((char*)d_ws + OFF_B_BYTES);
  float*  z0  = (float*) ((char*)d_ws + OFF_Z0_BYTES);
  float*  out = (float*)d_out;

  hipLaunchKernelGGL(k_setup, dim3(256),  dim3(TPB), 0, stream, protos, gridp, gatel, traw, clfw, ws);
  hipLaunchKernelGGL(k_prep,  dim3(1152), dim3(TPB), 0, stream, c3w, c4w, w3t, w4t);
  hipLaunchKernelGGL(k_conv1, dim3(4096), dim3(TPB), 0, stream, x,  c1w, c1b, h1);
  hipLaunchKernelGGL(k_conv2, dim3(4096), dim3(TPB), 0, stream, h1, c2w, c2b, h2c);
  for (int c = 0; c < 2; ++c) {
    hipLaunchKernelGGL(k_conv34, dim3(2048), dim3(TPB), 0, stream,
                       h2c, c3b, c4b, w3t, w4t, h4c, c*2048);
    hipLaunchKernelGGL(k_enc, dim3(128), dim3(TPB), 0, stream, h4c, encw, z0, c*2048);
  }
  hipLaunchKernelGGL(k_post, dim3(4096), dim3(TPB), 0, stream, z0, encb, nfw, nfb, protos, ws, clfb, out);
}

// Round 4
// 1052.308 us; speedup vs baseline: 8.8328x; 4.1281x over previous
//
#include <hip/hip_runtime.h>
#include <math.h>

#define TPB 256

typedef __attribute__((ext_vector_type(8))) short bf16x8;
typedef __attribute__((ext_vector_type(4))) float f32x4;

// ---------------- workspace layout ----------------
// aux (fp32), float offsets:
#define OFF_PN2   0          // 256
#define OFF_GN2   256        // 256
#define OFF_GATE  512        // 256
#define OFF_TEMP  768        // 1
#define OFF_WEFF  1024       // 2560
#define OFF_PT    4096       // 65536 protosT[d][j]
#define OFF_GT    69632      // 65536 gridT[d][j]
// bf16 weight tables (byte offsets):
#define OFF_W3T_BYTES 786432ul    // 9*128*64  bf16 = 147456 B
#define OFF_W4T_BYTES 983040ul    // 9*256*128 bf16 = 589824 B
#define OFF_EWT_BYTES 2097152ul   // ewt[n=256][k=16384] bf16 = 8 MiB
// big regions (byte offsets):
//  A: h1 bf16 (59 MB) then h4-chunk bf16 (64 MB);  B: h2 bf16 (32 MB);  Z: z0 fp32 (4 MB)
#define OFF_A_BYTES   12582912ul
#define OFF_B_BYTES   (OFF_A_BYTES + 67108864ul)
#define OFF_Z0_BYTES  (OFF_B_BYTES + 33554432ul)
// total ~112 MiB

// ---------------- bf16 helpers ----------------
__device__ __forceinline__ float bf2f(ushort u) {
  return __uint_as_float(((unsigned)u) << 16);
}
__device__ __forceinline__ ushort f2bf(float f) {   // RNE
  unsigned x = __float_as_uint(f);
  return (ushort)((x + 0x7fffu + ((x >> 16) & 1u)) >> 16);
}
__device__ __forceinline__ unsigned pack2(float a, float b) {
  return (unsigned)f2bf(a) | ((unsigned)f2bf(b) << 16);
}

// async global->LDS, 16B per lane; lds dest = wave-uniform base + lane*16
__device__ __forceinline__ void gload_lds16(const ushort* g, ushort* l) {
  __builtin_amdgcn_global_load_lds(
      (const __attribute__((address_space(1))) unsigned int*)g,
      (__attribute__((address_space(3))) unsigned int*)l, 16, 0, 0);
}

// ---------------- block reductions ----------------
__device__ __forceinline__ float block_sum(float v, float* red) {
  #pragma unroll
  for (int off = 32; off > 0; off >>= 1) v += __shfl_down(v, off, 64);
  int wid = threadIdx.x >> 6;
  __syncthreads();
  if ((threadIdx.x & 63) == 0) red[wid] = v;
  __syncthreads();
  return red[0] + red[1] + red[2] + red[3];
}
__device__ __forceinline__ float block_max(float v, float* red) {
  #pragma unroll
  for (int off = 32; off > 0; off >>= 1) v = fmaxf(v, __shfl_down(v, off, 64));
  int wid = threadIdx.x >> 6;
  __syncthreads();
  if ((threadIdx.x & 63) == 0) red[wid] = v;
  __syncthreads();
  return fmaxf(fmaxf(red[0], red[1]), fmaxf(red[2], red[3]));
}

// ---------------- setup (+ zero z0 for split-K atomics) ----------------
__global__ void __launch_bounds__(256) k_setup(const float* __restrict__ protos,
    const float* __restrict__ gridp, const float* __restrict__ gate_logits,
    const float* __restrict__ temp_raw, const float* __restrict__ clf_w,
    float* __restrict__ ws, float* __restrict__ z0) {
  __shared__ float red[4];
  int b = blockIdx.x, t = threadIdx.x;
  #pragma unroll
  for (int u = 0; u < 16; ++u) z0[(size_t)u*65536 + b*256 + t] = 0.f;
  float pv = protos[b*256 + t];
  float gv = gridp [b*256 + t];
  ws[OFF_PT + t*256 + b] = pv;
  ws[OFF_GT + t*256 + b] = gv;
  float sp = block_sum(pv*pv, red);
  float sg = block_sum(gv*gv, red);
  if (t == 0) {
    ws[OFF_PN2 + b] = sp;
    ws[OFF_GN2 + b] = sg;
    ws[OFF_GATE + b] = 1.f/(1.f + expf(-gate_logits[b]));
  }
  if (b == 0) {
    for (int i = t; i < 2560; i += TPB) {
      int d = i/10, c = i%10;
      ws[OFF_WEFF + i] = clf_w[d*10+c] + clf_w[(256+d)*10+c]
                       + clf_w[(512+d)*10+c] + clf_w[(768+d)*10+c];
    }
    if (t == 0) {
      float s = 1.f/(1.f + expf(-temp_raw[0]));
      ws[OFF_TEMP] = s*(1.f - 0.001f) + 0.001f;
    }
  }
}

// ---------------- prep: bf16 per-tap weight tables ----------------
__global__ void __launch_bounds__(256) k_prep(const float* __restrict__ w3,
    const float* __restrict__ w4, ushort* __restrict__ w3t, ushort* __restrict__ w4t) {
  int idx = blockIdx.x*256 + threadIdx.x;
  if (idx < 73728) {
    int tap = idx >> 13, r = idx & 8191, oc = r >> 6, ic = r & 63;
    w3t[idx] = f2bf(w3[oc*576 + ic*9 + tap]);
  }
  if (idx < 294912) {
    int tap = idx >> 15, r = idx & 32767, oc = r >> 7, ic = r & 127;
    w4t[idx] = f2bf(w4[oc*1152 + ic*9 + tap]);
  }
}

// ---------------- transpose enc_w -> ewt[n<256][k<16384] bf16 ----------------
__global__ void __launch_bounds__(256) k_trans(const float* __restrict__ ew,
    ushort* __restrict__ ewt) {
  __shared__ float tile[64][65];
  int kb = blockIdx.x, nb = blockIdx.y, t = threadIdx.x;
  #pragma unroll
  for (int i = 0; i < 16; ++i) {
    int idx = t + i*256, k = idx >> 6, n = idx & 63;
    tile[k][n] = ew[(size_t)(kb*64 + k)*256 + nb*64 + n];
  }
  __syncthreads();
  #pragma unroll
  for (int i = 0; i < 16; ++i) {
    int idx = t + i*256, n = idx >> 6, k = idx & 63;
    ewt[(size_t)(nb*64 + n)*16384 + kb*64 + k] = f2bf(tile[k][n]);
  }
}

// ---------------- conv1: 3x32x32 -> 32x15x15, k5 s2 p1, relu (out bf16) ----------------
__global__ void __launch_bounds__(256) k_conv1(const float* __restrict__ x,
    const float* __restrict__ w, const float* __restrict__ bias, ushort* __restrict__ h1) {
  __shared__ float xs[3072];
  __shared__ float wt[75*32];
  __shared__ float bs[32];
  int b = blockIdx.x, t = threadIdx.x;
  for (int i = t; i < 3072; i += TPB) xs[i] = x[(size_t)b*3072 + i];
  for (int i = t; i < 2400; i += TPB) { int oc = i/75, j = i%75; wt[j*32 + oc] = w[i]; }
  if (t < 32) bs[t] = bias[t];
  __syncthreads();
  if (t < 225) {
    int oy = t/15, ox = t%15;
    float acc[32];
    #pragma unroll
    for (int o = 0; o < 32; ++o) acc[o] = bs[o];
    for (int ic = 0; ic < 3; ++ic)
      for (int ky = 0; ky < 5; ++ky) {
        int iy = 2*oy - 1 + ky;
        if (iy < 0 || iy > 31) continue;
        for (int kx = 0; kx < 5; ++kx) {
          int ix = 2*ox - 1 + kx;
          if (ix < 0 || ix > 31) continue;
          float xv = xs[ic*1024 + iy*32 + ix];
          const float4* wp = (const float4*)&wt[(ic*25 + ky*5 + kx)*32];
          #pragma unroll
          for (int g = 0; g < 8; ++g) {
            float4 w4 = wp[g];
            acc[g*4+0] += xv*w4.x; acc[g*4+1] += xv*w4.y;
            acc[g*4+2] += xv*w4.z; acc[g*4+3] += xv*w4.w;
          }
        }
      }
    #pragma unroll
    for (int o = 0; o < 32; ++o) h1[(size_t)b*7200 + o*225 + t] = f2bf(fmaxf(acc[o], 0.f));
  }
}

// ---------------- conv2: 32x15x15 -> 64x8x8, k3 s2 p1, relu, OUT CHANNEL-LAST ----------
__global__ void __launch_bounds__(256) k_conv2(const ushort* __restrict__ h1,
    const float* __restrict__ w, const float* __restrict__ bias, ushort* __restrict__ h2c) {
  __shared__ float xp[32*17*20];   // 43.5 KB
  __shared__ float wt[72*65];      // 18.7 KB
  int b = blockIdx.x, t = threadIdx.x;
  for (int i = t; i < 32*17*20; i += TPB) xp[i] = 0.f;
  __syncthreads();
  for (int i = t; i < 7200; i += TPB) {
    int ic = i/225, p = i%225, iy = p/15, ix = p%15;
    xp[ic*340 + (iy+1)*20 + (ix+1)] = bf2f(h1[(size_t)b*7200 + i]);
  }
  int py = t >> 5, og = t & 31;
  float acc[2][8];
  #pragma unroll
  for (int o = 0; o < 2; ++o) {
    float bv = bias[og + 32*o];
    #pragma unroll
    for (int px = 0; px < 8; ++px) acc[o][px] = bv;
  }
  for (int icc = 0; icc < 4; ++icc) {
    __syncthreads();
    for (int i = t; i < 8*9*64; i += TPB) {
      int oc = i/72, r = i%72;
      wt[r*65 + oc] = w[oc*288 + icc*72 + r];
    }
    __syncthreads();
    for (int icl = 0; icl < 8; ++icl) {
      int ic = icc*8 + icl;
      #pragma unroll
      for (int ky = 0; ky < 3; ++ky) {
        const float4* rp = (const float4*)&xp[ic*340 + (2*py + ky)*20];
        float rr[20];
        #pragma unroll
        for (int g = 0; g < 5; ++g) ((float4*)rr)[g] = rp[g];
        #pragma unroll
        for (int kx = 0; kx < 3; ++kx) {
          int rbase = (icl*9 + ky*3 + kx)*65 + og;
          float w0 = wt[rbase], w1v = wt[rbase + 32];
          #pragma unroll
          for (int px = 0; px < 8; ++px) {
            float xv = rr[2*px + kx];
            acc[0][px] += xv*w0; acc[1][px] += xv*w1v;
          }
        }
      }
    }
  }
  #pragma unroll
  for (int o = 0; o < 2; ++o) {
    int oc = og + 32*o;
    #pragma unroll
    for (int px = 0; px < 8; ++px)
      h2c[(size_t)b*4096 + (py*8+px)*64 + oc] = f2bf(fmaxf(acc[o][px], 0.f));
  }
}

// ---------------- conv3+conv4 fused, MFMA implicit-GEMM ----------------
__global__ void __launch_bounds__(256) k_conv34(const ushort* __restrict__ h2c,
    const float* __restrict__ b3, const float* __restrict__ b4,
    const ushort* __restrict__ w3t, const ushort* __restrict__ w4t,
    ushort* __restrict__ h4c, int img_base) {
  __shared__ ushort xp [100*72];    // 14400 B
  __shared__ ushort h3p[100*136];   // 27200 B
  int b = img_base + blockIdx.x, t = threadIdx.x;
  for (int i = t; i < 3600; i += TPB) ((unsigned*)xp)[i]  = 0u;
  for (int i = t; i < 6800; i += TPB) ((unsigned*)h3p)[i] = 0u;
  __syncthreads();
  #pragma unroll
  for (int u = 0; u < 2; ++u) {
    int i = t + u*256;
    int px = i >> 3, icq = i & 7;
    int iy = px >> 3, ix = px & 7;
    bf16x8 v = *(const bf16x8*)&h2c[(size_t)b*4096 + (size_t)px*64 + icq*8];
    *(bf16x8*)&xp[((iy+1)*10 + ix + 1)*72 + icq*8] = v;
  }
  __syncthreads();

  const int lane = t & 63, wv = t >> 6;
  const int quad = lane >> 4, row16 = lane & 15;
  int aoy[4], aox[4];
  #pragma unroll
  for (int mt = 0; mt < 4; ++mt) {
    int px = mt*16 + row16;
    aoy[mt] = px >> 3; aox[mt] = px & 7;
  }

  // ---- conv3 ----
  f32x4 c3[4][2];
  #pragma unroll
  for (int mt = 0; mt < 4; ++mt) { c3[mt][0] = (f32x4)0.f; c3[mt][1] = (f32x4)0.f; }
  for (int ky = 0; ky < 3; ++ky)
    for (int kx = 0; kx < 3; ++kx) {
      int tap = ky*3 + kx;
      const ushort* wb = w3t + tap*8192 + (wv*32 + row16)*64 + quad*8;
      #pragma unroll
      for (int ks = 0; ks < 2; ++ks) {
        bf16x8 bf0 = *(const bf16x8*)(wb + ks*32);
        bf16x8 bf1 = *(const bf16x8*)(wb + 1024 + ks*32);
        #pragma unroll
        for (int mt = 0; mt < 4; ++mt) {
          bf16x8 af = *(const bf16x8*)&xp[((aoy[mt]+ky)*10 + aox[mt]+kx)*72 + ks*32 + quad*8];
          c3[mt][0] = __builtin_amdgcn_mfma_f32_16x16x32_bf16(af, bf0, c3[mt][0], 0, 0, 0);
          c3[mt][1] = __builtin_amdgcn_mfma_f32_16x16x32_bf16(af, bf1, c3[mt][1], 0, 0, 0);
        }
      }
    }
  #pragma unroll
  for (int nt = 0; nt < 2; ++nt) {
    int oc = wv*32 + nt*16 + row16;
    float bv = b3[oc];
    #pragma unroll
    for (int mt = 0; mt < 4; ++mt)
      #pragma unroll
      for (int r = 0; r < 4; ++r) {
        int px = mt*16 + quad*4 + r;
        int oy = px >> 3, ox = px & 7;
        h3p[((oy+1)*10 + ox + 1)*136 + oc] = f2bf(fmaxf(c3[mt][nt][r] + bv, 0.f));
      }
  }
  __syncthreads();

  // ---- conv4 ----
  f32x4 c4[4][4];
  #pragma unroll
  for (int mt = 0; mt < 4; ++mt)
    #pragma unroll
    for (int nt = 0; nt < 4; ++nt) c4[mt][nt] = (f32x4)0.f;
  for (int ky = 0; ky < 3; ++ky)
    for (int kx = 0; kx < 3; ++kx) {
      int tap = ky*3 + kx;
      const ushort* wb = w4t + tap*32768 + (wv*64 + row16)*128 + quad*8;
      #pragma unroll
      for (int ks = 0; ks < 4; ++ks) {
        bf16x8 bf[4];
        #pragma unroll
        for (int nt = 0; nt < 4; ++nt)
          bf[nt] = *(const bf16x8*)(wb + nt*2048 + ks*32);
        #pragma unroll
        for (int mt = 0; mt < 4; ++mt) {
          bf16x8 af = *(const bf16x8*)&h3p[((aoy[mt]+ky)*10 + aox[mt]+kx)*136 + ks*32 + quad*8];
          #pragma unroll
          for (int nt = 0; nt < 4; ++nt)
            c4[mt][nt] = __builtin_amdgcn_mfma_f32_16x16x32_bf16(af, bf[nt], c4[mt][nt], 0, 0, 0);
        }
      }
    }
  int bl = blockIdx.x;
  #pragma unroll
  for (int nt = 0; nt < 4; ++nt) {
    int oc = wv*64 + nt*16 + row16;
    float bv = b4[oc];
    #pragma unroll
    for (int mt = 0; mt < 4; ++mt) {
      int px0 = mt*16 + quad*4;
      uint2 dd;
      dd.x = pack2(fmaxf(c4[mt][nt][0] + bv, 0.f), fmaxf(c4[mt][nt][1] + bv, 0.f));
      dd.y = pack2(fmaxf(c4[mt][nt][2] + bv, 0.f), fmaxf(c4[mt][nt][3] + bv, 0.f));
      *(uint2*)&h4c[(size_t)bl*16384 + oc*64 + px0] = dd;
    }
  }
}

// ---------------- enc: z0 += h4c @ ewt^T, MFMA bf16, split-K=8, 128x128 tiles ------
// grid 256: bx = slice(3b) | mb(4b) | nb(1b). Each block: M0=mb*128 (local to chunk),
// N0=nb*128, K-slice = slice*2048 .. +2048, BK=64 staged via global_load_lds with
// XOR-swizzled source so frag ds_read_b128 are conflict-free.
__global__ void __launch_bounds__(256) k_enc(const ushort* __restrict__ h4c,
    const ushort* __restrict__ ewt, float* __restrict__ z0, int img_base) {
  __shared__ ushort a_s[128*64];   // 16 KB
  __shared__ ushort b_s[128*64];   // 16 KB
  const int t = threadIdx.x, bx = blockIdx.x;
  const int slice = bx & 7;
  const int mb = (bx >> 3) & 15;
  const int nb = bx >> 7;
  const int M0 = mb*128, N0 = nb*128;
  const int kbase = slice*2048;
  const int lane = t & 63, wv = t >> 6;
  const int quad = lane >> 4, row16 = lane & 15;
  const int mrow0 = (wv & 1)*64, ncol0 = (wv >> 1)*64;
  const int sr = lane >> 3, sp = lane & 7;   // staging: row-in-8, phys 16B chunk

  f32x4 acc[4][4];
  #pragma unroll
  for (int mt = 0; mt < 4; ++mt)
    #pragma unroll
    for (int nt = 0; nt < 4; ++nt) acc[mt][nt] = (f32x4)0.f;

  for (int kt = 0; kt < 32; ++kt) {
    const int k0 = kbase + kt*64;
    __syncthreads();                       // prior frag reads done
    #pragma unroll
    for (int u = 0; u < 4; ++u) {
      int r = wv*32 + u*8 + sr;            // row 0..127
      int c = sp ^ (r & 7);                // logical 16B chunk for this phys slot
      gload_lds16(&h4c[(size_t)(M0 + r)*16384 + k0 + c*8], &a_s[(wv*32 + u*8)*64]);
      gload_lds16(&ewt[(size_t)(N0 + r)*16384 + k0 + c*8], &b_s[(wv*32 + u*8)*64]);
    }
    __syncthreads();                       // vmcnt drain + all staged
    #pragma unroll
    for (int ks = 0; ks < 2; ++ks) {
      bf16x8 af[4], bf[4];
      #pragma unroll
      for (int mt = 0; mt < 4; ++mt) {
        int r = mrow0 + mt*16 + row16;
        int p = (ks*4 + quad) ^ (r & 7);
        af[mt] = *(const bf16x8*)&a_s[r*64 + p*8];
      }
      #pragma unroll
      for (int nt = 0; nt < 4; ++nt) {
        int r = ncol0 + nt*16 + row16;
        int p = (ks*4 + quad) ^ (r & 7);
        bf[nt] = *(const bf16x8*)&b_s[r*64 + p*8];
      }
      #pragma unroll
      for (int mt = 0; mt < 4; ++mt)
        #pragma unroll
        for (int nt = 0; nt < 4; ++nt)
          acc[mt][nt] = __builtin_amdgcn_mfma_f32_16x16x32_bf16(af[mt], bf[nt], acc[mt][nt], 0, 0, 0);
    }
  }
  #pragma unroll
  for (int mt = 0; mt < 4; ++mt) {
    int mrow = M0 + mrow0 + mt*16 + quad*4;
    #pragma unroll
    for (int nt = 0; nt < 4; ++nt) {
      int col = N0 + ncol0 + nt*16 + row16;
      #pragma unroll
      for (int r = 0; r < 4; ++r)
        atomicAdd(&z0[(size_t)(img_base + mrow + r)*256 + col], acc[mt][nt][r]);
    }
  }
}

// ---------------- post ----------------
__global__ void __launch_bounds__(256) k_post(const float* __restrict__ z0,
    const float* __restrict__ enc_b, const float* __restrict__ nfw,
    const float* __restrict__ nfb, const float* __restrict__ protos,
    const float* __restrict__ ws, const float* __restrict__ clf_b,
    float* __restrict__ out) {
  __shared__ float z0s[256], zs[256], wj[256], bls[256];
  __shared__ float red[4];
  int b = blockIdx.x, t = threadIdx.x;
  z0s[t] = z0[(size_t)b*256 + t] + enc_b[t];
  __syncthreads();
  float zv = nfb[t];
  for (int e = 0; e < 256; ++e) zv += z0s[e]*nfw[e*256 + t];
  zs[t] = zv;
  float z2 = block_sum(zv*zv, red);
  const float* pT = ws + OFF_PT;
  const float* gT = ws + OFF_GT;
  float dp = 0.f, dg = 0.f;
  for (int d = 0; d < 256; ++d) {
    float zd = zs[d];
    dp += zd*pT[d*256 + t];
    dg += zd*gT[d*256 + t];
  }
  float d2p = z2 + ws[OFF_PN2 + t] - 2.f*dp;
  float d2g = z2 + ws[OFF_GN2 + t] - 2.f*dg;
  float dtot = sqrtf(fmaxf(d2p, 0.f)) + sqrtf(fmaxf(d2g, 0.f));
  float l = -dtot / ws[OFF_TEMP];
  float m  = block_max(l, red);
  float e  = expf(l - m);
  float E  = block_sum(e, red);
  float w1 = (e/E)*ws[OFF_GATE + t];
  float W  = block_sum(w1, red);
  float wv = w1/(W + 1e-8f);
  wj[t] = wv;
  __syncthreads();
  float bl = 0.f;
  for (int j = 0; j < 256; ++j) bl += wj[j]*protos[j*256 + t];
  bls[t] = bl;
  __syncthreads();
  if (t < 10) {
    float s = clf_b[t];
    for (int d = 0; d < 256; ++d) s += bls[d]*ws[OFF_WEFF + d*10 + t];
    out[(size_t)b*10 + t] = s;
  }
}

extern "C" void kernel_launch(void* const* d_in, const int* in_sizes, int n_in,
                              void* d_out, int out_size, void* d_ws, size_t ws_size,
                              hipStream_t stream) {
  (void)in_sizes; (void)n_in; (void)out_size; (void)ws_size;
  const float* x      = (const float*)d_in[0];
  const float* c1w    = (const float*)d_in[2];
  const float* c1b    = (const float*)d_in[3];
  const float* c2w    = (const float*)d_in[4];
  const float* c2b    = (const float*)d_in[5];
  const float* c3w    = (const float*)d_in[6];
  const float* c3b    = (const float*)d_in[7];
  const float* c4w    = (const float*)d_in[8];
  const float* c4b    = (const float*)d_in[9];
  const float* encw   = (const float*)d_in[10];
  const float* encb   = (const float*)d_in[11];
  // d_in[12..17] dead: softmax over a single node == 1 exactly
  const float* clfw   = (const float*)d_in[18];
  const float* clfb   = (const float*)d_in[19];
  const float* nfw    = (const float*)d_in[20];
  const float* nfb    = (const float*)d_in[21];
  const float* protos = (const float*)d_in[22];
  const float* gridp  = (const float*)d_in[23];
  const float* traw   = (const float*)d_in[24];
  const float* gatel  = (const float*)d_in[25];

  float*  ws  = (float*)d_ws;
  ushort* w3t = (ushort*)((char*)d_ws + OFF_W3T_BYTES);
  ushort* w4t = (ushort*)((char*)d_ws + OFF_W4T_BYTES);
  ushort* ewt = (ushort*)((char*)d_ws + OFF_EWT_BYTES);
  ushort* h1  = (ushort*)((char*)d_ws + OFF_A_BYTES);
  ushort* h4c = (ushort*)((char*)d_ws + OFF_A_BYTES);   // reuses h1 region
  ushort* h2c = (ushort*)((char*)d_ws + OFF_B_BYTES);
  float*  z0  = (float*) ((char*)d_ws + OFF_Z0_BYTES);
  float*  out = (float*)d_out;

  hipLaunchKernelGGL(k_setup, dim3(256),  dim3(TPB), 0, stream, protos, gridp, gatel, traw, clfw, ws, z0);
  hipLaunchKernelGGL(k_prep,  dim3(1152), dim3(TPB), 0, stream, c3w, c4w, w3t, w4t);
  hipLaunchKernelGGL(k_trans, dim3(256, 4), dim3(TPB), 0, stream, encw, ewt);
  hipLaunchKernelGGL(k_conv1, dim3(4096), dim3(TPB), 0, stream, x,  c1w, c1b, h1);
  hipLaunchKernelGGL(k_conv2, dim3(4096), dim3(TPB), 0, stream, h1, c2w, c2b, h2c);
  for (int c = 0; c < 2; ++c) {
    hipLaunchKernelGGL(k_conv34, dim3(2048), dim3(TPB), 0, stream,
                       h2c, c3b, c4b, w3t, w4t, h4c, c*2048);
    hipLaunchKernelGGL(k_enc, dim3(256), dim3(TPB), 0, stream, h4c, ewt, z0, c*2048);
  }
  hipLaunchKernelGGL(k_post, dim3(4096), dim3(TPB), 0, stream, z0, encb, nfw, nfb, protos, ws, clfb, out);
}

// Round 5
// 870.382 us; speedup vs baseline: 10.6791x; 1.2090x over previous
//
#include <hip/hip_runtime.h>
#include <math.h>

#define TPB 256

typedef __attribute__((ext_vector_type(8))) short bf16x8;
typedef __attribute__((ext_vector_type(4))) float f32x4;

// ---------------- workspace layout ----------------
// aux (fp32), float offsets:
#define OFF_PN2   0          // 256
#define OFF_GN2   256        // 256
#define OFF_GATE  512        // 256
#define OFF_TEMP  768        // 1
#define OFF_WEFF  1024       // 2560
#define OFF_PT    4096       // 65536 protosT[d][j]
#define OFF_GT    69632      // 65536 gridT[d][j]
// bf16 weight tables (byte offsets):
#define OFF_W2T_BYTES 737280ul    // 9*64*32   bf16 = 36864 B
#define OFF_W3T_BYTES 786432ul    // 9*128*64  bf16 = 147456 B
#define OFF_W4T_BYTES 983040ul    // 9*256*128 bf16 = 589824 B
#define OFF_EWT_BYTES 2097152ul   // ewt[n=256][k=16384] bf16 = 8 MiB
// big regions (byte offsets):
//  A: h4-chunk bf16 (64 MB);  B: h2 bf16 (32 MB);  Z: z0 fp32 (4 MB)
#define OFF_A_BYTES   12582912ul
#define OFF_B_BYTES   (OFF_A_BYTES + 67108864ul)
#define OFF_Z0_BYTES  (OFF_B_BYTES + 33554432ul)
// total ~112 MiB

// ---------------- bf16 helpers ----------------
__device__ __forceinline__ float bf2f(ushort u) {
  return __uint_as_float(((unsigned)u) << 16);
}
__device__ __forceinline__ ushort f2bf(float f) {   // RNE
  unsigned x = __float_as_uint(f);
  return (ushort)((x + 0x7fffu + ((x >> 16) & 1u)) >> 16);
}
__device__ __forceinline__ unsigned pack2(float a, float b) {
  return (unsigned)f2bf(a) | ((unsigned)f2bf(b) << 16);
}

// async global->LDS, 16B per lane; lds dest = wave-uniform base + lane*16
__device__ __forceinline__ void gload_lds16(const ushort* g, ushort* l) {
  __builtin_amdgcn_global_load_lds(
      (const __attribute__((address_space(1))) unsigned int*)g,
      (__attribute__((address_space(3))) unsigned int*)l, 16, 0, 0);
}

// ---------------- block reductions ----------------
__device__ __forceinline__ float block_sum(float v, float* red) {
  #pragma unroll
  for (int off = 32; off > 0; off >>= 1) v += __shfl_down(v, off, 64);
  int wid = threadIdx.x >> 6;
  __syncthreads();
  if ((threadIdx.x & 63) == 0) red[wid] = v;
  __syncthreads();
  return red[0] + red[1] + red[2] + red[3];
}
__device__ __forceinline__ float block_max(float v, float* red) {
  #pragma unroll
  for (int off = 32; off > 0; off >>= 1) v = fmaxf(v, __shfl_down(v, off, 64));
  int wid = threadIdx.x >> 6;
  __syncthreads();
  if ((threadIdx.x & 63) == 0) red[wid] = v;
  __syncthreads();
  return fmaxf(fmaxf(red[0], red[1]), fmaxf(red[2], red[3]));
}

// ---------------- setup (+ zero z0 for split-K atomics) ----------------
__global__ void __launch_bounds__(256) k_setup(const float* __restrict__ protos,
    const float* __restrict__ gridp, const float* __restrict__ gate_logits,
    const float* __restrict__ temp_raw, const float* __restrict__ clf_w,
    float* __restrict__ ws, float* __restrict__ z0) {
  __shared__ float red[4];
  int b = blockIdx.x, t = threadIdx.x;
  #pragma unroll
  for (int u = 0; u < 16; ++u) z0[(size_t)u*65536 + b*256 + t] = 0.f;
  float pv = protos[b*256 + t];
  float gv = gridp [b*256 + t];
  ws[OFF_PT + t*256 + b] = pv;
  ws[OFF_GT + t*256 + b] = gv;
  float sp = block_sum(pv*pv, red);
  float sg = block_sum(gv*gv, red);
  if (t == 0) {
    ws[OFF_PN2 + b] = sp;
    ws[OFF_GN2 + b] = sg;
    ws[OFF_GATE + b] = 1.f/(1.f + expf(-gate_logits[b]));
  }
  if (b == 0) {
    for (int i = t; i < 2560; i += TPB) {
      int d = i/10, c = i%10;
      ws[OFF_WEFF + i] = clf_w[d*10+c] + clf_w[(256+d)*10+c]
                       + clf_w[(512+d)*10+c] + clf_w[(768+d)*10+c];
    }
    if (t == 0) {
      float s = 1.f/(1.f + expf(-temp_raw[0]));
      ws[OFF_TEMP] = s*(1.f - 0.001f) + 0.001f;
    }
  }
}

// ---------------- prep: bf16 per-tap weight tables (conv2/3/4) ----------------
__global__ void __launch_bounds__(256) k_prep(const float* __restrict__ w2,
    const float* __restrict__ w3, const float* __restrict__ w4,
    ushort* __restrict__ w2t, ushort* __restrict__ w3t, ushort* __restrict__ w4t) {
  int idx = blockIdx.x*256 + threadIdx.x;
  if (idx < 18432) {
    int tap = idx >> 11, r = idx & 2047, oc = r >> 5, ic = r & 31;
    w2t[idx] = f2bf(w2[oc*288 + ic*9 + tap]);
  }
  if (idx < 73728) {
    int tap = idx >> 13, r = idx & 8191, oc = r >> 6, ic = r & 63;
    w3t[idx] = f2bf(w3[oc*576 + ic*9 + tap]);
  }
  if (idx < 294912) {
    int tap = idx >> 15, r = idx & 32767, oc = r >> 7, ic = r & 127;
    w4t[idx] = f2bf(w4[oc*1152 + ic*9 + tap]);
  }
}

// ---------------- transpose enc_w -> ewt[n<256][k<16384] bf16 ----------------
__global__ void __launch_bounds__(256) k_trans(const float* __restrict__ ew,
    ushort* __restrict__ ewt) {
  __shared__ float tile[64][65];
  int kb = blockIdx.x, nb = blockIdx.y, t = threadIdx.x;
  #pragma unroll
  for (int i = 0; i < 16; ++i) {
    int idx = t + i*256, k = idx >> 6, n = idx & 63;
    tile[k][n] = ew[(size_t)(kb*64 + k)*256 + nb*64 + n];
  }
  __syncthreads();
  #pragma unroll
  for (int i = 0; i < 16; ++i) {
    int idx = t + i*256, n = idx >> 6, k = idx & 63;
    ewt[(size_t)(nb*64 + n)*16384 + kb*64 + k] = f2bf(tile[k][n]);
  }
}

// ---------------- conv1+conv2 fused: x -> (h1 in LDS) -> h2c channel-last ----------
// conv1: 3x32x32 -> 32x15x15 (k5 s2 p1, relu), fp32 vector, written bf16 channel-last
//        into padded LDS xs[17][17][40] (halo zero, cell 80B = 16B aligned).
// conv2: 32ch -> 64ch (k3 s2 p1, relu), per-tap MFMA implicit-GEMM, B from global w2t.
__global__ void __launch_bounds__(256) k_conv12(const float* __restrict__ x,
    const float* __restrict__ w1, const float* __restrict__ b1,
    const ushort* __restrict__ w2t, const float* __restrict__ b2,
    ushort* __restrict__ h2c) {
  __shared__ float  xin[3072];      // 12288 B
  __shared__ float  wt1[75*32];     // 9600 B
  __shared__ float  bs1[32];
  __shared__ ushort xs[17*17*40];   // 23120 B  (total ~45.1 KB)
  int b = blockIdx.x, t = threadIdx.x;
  for (int i = t; i < 5780; i += TPB) ((unsigned*)xs)[i] = 0u;
  for (int i = t; i < 3072; i += TPB) xin[i] = x[(size_t)b*3072 + i];
  for (int i = t; i < 2400; i += TPB) { int oc = i/75, j = i%75; wt1[j*32 + oc] = w1[i]; }
  if (t < 32) bs1[t] = b1[t];
  __syncthreads();

  if (t < 225) {               // conv1: one px per thread, all 32 oc
    int oy = t/15, ox = t%15;
    float acc[32];
    #pragma unroll
    for (int o = 0; o < 32; ++o) acc[o] = bs1[o];
    for (int ic = 0; ic < 3; ++ic)
      for (int ky = 0; ky < 5; ++ky) {
        int iy = 2*oy - 1 + ky;
        if (iy < 0 || iy > 31) continue;
        for (int kx = 0; kx < 5; ++kx) {
          int ix = 2*ox - 1 + kx;
          if (ix < 0 || ix > 31) continue;
          float xv = xin[ic*1024 + iy*32 + ix];
          const float4* wp = (const float4*)&wt1[(ic*25 + ky*5 + kx)*32];
          #pragma unroll
          for (int g = 0; g < 8; ++g) {
            float4 w4 = wp[g];
            acc[g*4+0] += xv*w4.x; acc[g*4+1] += xv*w4.y;
            acc[g*4+2] += xv*w4.z; acc[g*4+3] += xv*w4.w;
          }
        }
      }
    unsigned pk[16];
    #pragma unroll
    for (int g = 0; g < 16; ++g)
      pk[g] = pack2(fmaxf(acc[2*g], 0.f), fmaxf(acc[2*g+1], 0.f));
    ushort* cell = &xs[((oy+1)*17 + (ox+1))*40];
    #pragma unroll
    for (int q = 0; q < 4; ++q) *(uint4*)(cell + q*8) = ((uint4*)pk)[q];
  }
  __syncthreads();

  // conv2 MFMA: wave w -> oc [w*16, w*16+16), 4 M-tiles of 16 px
  const int lane = t & 63, w = t >> 6;
  const int quad = lane >> 4, row16 = lane & 15;
  f32x4 acc2[4];
  #pragma unroll
  for (int mt = 0; mt < 4; ++mt) acc2[mt] = (f32x4)0.f;
  #pragma unroll
  for (int ky = 0; ky < 3; ++ky)
    #pragma unroll
    for (int kx = 0; kx < 3; ++kx) {
      int tap = ky*3 + kx;
      bf16x8 bf = *(const bf16x8*)&w2t[tap*2048 + (w*16 + row16)*32 + quad*8];
      #pragma unroll
      for (int mt = 0; mt < 4; ++mt) {
        int px = mt*16 + row16;
        int iy = 2*(px >> 3) + ky, ix = 2*(px & 7) + kx;
        bf16x8 af = *(const bf16x8*)&xs[(iy*17 + ix)*40 + quad*8];
        acc2[mt] = __builtin_amdgcn_mfma_f32_16x16x32_bf16(af, bf, acc2[mt], 0, 0, 0);
      }
    }
  int oc = w*16 + row16;
  float bv = b2[oc];
  #pragma unroll
  for (int mt = 0; mt < 4; ++mt)
    #pragma unroll
    for (int r = 0; r < 4; ++r) {
      int px = mt*16 + quad*4 + r;
      h2c[(size_t)b*4096 + px*64 + oc] = f2bf(fmaxf(acc2[mt][r] + bv, 0.f));
    }
}

// ---------------- conv3+conv4 fused, MFMA implicit-GEMM ----------------
__global__ void __launch_bounds__(256) k_conv34(const ushort* __restrict__ h2c,
    const float* __restrict__ b3, const float* __restrict__ b4,
    const ushort* __restrict__ w3t, const ushort* __restrict__ w4t,
    ushort* __restrict__ h4c, int img_base) {
  __shared__ ushort xp [100*72];    // 14400 B
  __shared__ ushort h3p[100*136];   // 27200 B
  int b = img_base + blockIdx.x, t = threadIdx.x;
  for (int i = t; i < 3600; i += TPB) ((unsigned*)xp)[i]  = 0u;
  for (int i = t; i < 6800; i += TPB) ((unsigned*)h3p)[i] = 0u;
  __syncthreads();
  #pragma unroll
  for (int u = 0; u < 2; ++u) {
    int i = t + u*256;
    int px = i >> 3, icq = i & 7;
    int iy = px >> 3, ix = px & 7;
    bf16x8 v = *(const bf16x8*)&h2c[(size_t)b*4096 + (size_t)px*64 + icq*8];
    *(bf16x8*)&xp[((iy+1)*10 + ix + 1)*72 + icq*8] = v;
  }
  __syncthreads();

  const int lane = t & 63, wv = t >> 6;
  const int quad = lane >> 4, row16 = lane & 15;
  int aoy[4], aox[4];
  #pragma unroll
  for (int mt = 0; mt < 4; ++mt) {
    int px = mt*16 + row16;
    aoy[mt] = px >> 3; aox[mt] = px & 7;
  }

  // ---- conv3 ----
  f32x4 c3[4][2];
  #pragma unroll
  for (int mt = 0; mt < 4; ++mt) { c3[mt][0] = (f32x4)0.f; c3[mt][1] = (f32x4)0.f; }
  for (int ky = 0; ky < 3; ++ky)
    for (int kx = 0; kx < 3; ++kx) {
      int tap = ky*3 + kx;
      const ushort* wb = w3t + tap*8192 + (wv*32 + row16)*64 + quad*8;
      #pragma unroll
      for (int ks = 0; ks < 2; ++ks) {
        bf16x8 bf0 = *(const bf16x8*)(wb + ks*32);
        bf16x8 bf1 = *(const bf16x8*)(wb + 1024 + ks*32);
        #pragma unroll
        for (int mt = 0; mt < 4; ++mt) {
          bf16x8 af = *(const bf16x8*)&xp[((aoy[mt]+ky)*10 + aox[mt]+kx)*72 + ks*32 + quad*8];
          c3[mt][0] = __builtin_amdgcn_mfma_f32_16x16x32_bf16(af, bf0, c3[mt][0], 0, 0, 0);
          c3[mt][1] = __builtin_amdgcn_mfma_f32_16x16x32_bf16(af, bf1, c3[mt][1], 0, 0, 0);
        }
      }
    }
  #pragma unroll
  for (int nt = 0; nt < 2; ++nt) {
    int oc = wv*32 + nt*16 + row16;
    float bv = b3[oc];
    #pragma unroll
    for (int mt = 0; mt < 4; ++mt)
      #pragma unroll
      for (int r = 0; r < 4; ++r) {
        int px = mt*16 + quad*4 + r;
        int oy = px >> 3, ox = px & 7;
        h3p[((oy+1)*10 + ox + 1)*136 + oc] = f2bf(fmaxf(c3[mt][nt][r] + bv, 0.f));
      }
  }
  __syncthreads();

  // ---- conv4 ----
  f32x4 c4[4][4];
  #pragma unroll
  for (int mt = 0; mt < 4; ++mt)
    #pragma unroll
    for (int nt = 0; nt < 4; ++nt) c4[mt][nt] = (f32x4)0.f;
  for (int ky = 0; ky < 3; ++ky)
    for (int kx = 0; kx < 3; ++kx) {
      int tap = ky*3 + kx;
      const ushort* wb = w4t + tap*32768 + (wv*64 + row16)*128 + quad*8;
      #pragma unroll
      for (int ks = 0; ks < 4; ++ks) {
        bf16x8 bf[4];
        #pragma unroll
        for (int nt = 0; nt < 4; ++nt)
          bf[nt] = *(const bf16x8*)(wb + nt*2048 + ks*32);
        #pragma unroll
        for (int mt = 0; mt < 4; ++mt) {
          bf16x8 af = *(const bf16x8*)&h3p[((aoy[mt]+ky)*10 + aox[mt]+kx)*136 + ks*32 + quad*8];
          #pragma unroll
          for (int nt = 0; nt < 4; ++nt)
            c4[mt][nt] = __builtin_amdgcn_mfma_f32_16x16x32_bf16(af, bf[nt], c4[mt][nt], 0, 0, 0);
        }
      }
    }
  int bl = blockIdx.x;
  #pragma unroll
  for (int nt = 0; nt < 4; ++nt) {
    int oc = wv*64 + nt*16 + row16;
    float bv = b4[oc];
    #pragma unroll
    for (int mt = 0; mt < 4; ++mt) {
      int px0 = mt*16 + quad*4;
      uint2 dd;
      dd.x = pack2(fmaxf(c4[mt][nt][0] + bv, 0.f), fmaxf(c4[mt][nt][1] + bv, 0.f));
      dd.y = pack2(fmaxf(c4[mt][nt][2] + bv, 0.f), fmaxf(c4[mt][nt][3] + bv, 0.f));
      *(uint2*)&h4c[(size_t)bl*16384 + oc*64 + px0] = dd;
    }
  }
}

// ---------------- enc: z0 += h4c @ ewt^T, MFMA bf16, split-K=8, 128x128 tiles ------
__global__ void __launch_bounds__(256) k_enc(const ushort* __restrict__ h4c,
    const ushort* __restrict__ ewt, float* __restrict__ z0, int img_base) {
  __shared__ ushort a_s[128*64];   // 16 KB
  __shared__ ushort b_s[128*64];   // 16 KB
  const int t = threadIdx.x, bx = blockIdx.x;
  const int slice = bx & 7;
  const int mb = (bx >> 3) & 15;
  const int nb = bx >> 7;
  const int M0 = mb*128, N0 = nb*128;
  const int kbase = slice*2048;
  const int lane = t & 63, wv = t >> 6;
  const int quad = lane >> 4, row16 = lane & 15;
  const int mrow0 = (wv & 1)*64, ncol0 = (wv >> 1)*64;
  const int sr = lane >> 3, sp = lane & 7;

  f32x4 acc[4][4];
  #pragma unroll
  for (int mt = 0; mt < 4; ++mt)
    #pragma unroll
    for (int nt = 0; nt < 4; ++nt) acc[mt][nt] = (f32x4)0.f;

  for (int kt = 0; kt < 32; ++kt) {
    const int k0 = kbase + kt*64;
    __syncthreads();
    #pragma unroll
    for (int u = 0; u < 4; ++u) {
      int r = wv*32 + u*8 + sr;
      int c = sp ^ (r & 7);
      gload_lds16(&h4c[(size_t)(M0 + r)*16384 + k0 + c*8], &a_s[(wv*32 + u*8)*64]);
      gload_lds16(&ewt[(size_t)(N0 + r)*16384 + k0 + c*8], &b_s[(wv*32 + u*8)*64]);
    }
    __syncthreads();
    #pragma unroll
    for (int ks = 0; ks < 2; ++ks) {
      bf16x8 af[4], bf[4];
      #pragma unroll
      for (int mt = 0; mt < 4; ++mt) {
        int r = mrow0 + mt*16 + row16;
        int p = (ks*4 + quad) ^ (r & 7);
        af[mt] = *(const bf16x8*)&a_s[r*64 + p*8];
      }
      #pragma unroll
      for (int nt = 0; nt < 4; ++nt) {
        int r = ncol0 + nt*16 + row16;
        int p = (ks*4 + quad) ^ (r & 7);
        bf[nt] = *(const bf16x8*)&b_s[r*64 + p*8];
      }
      #pragma unroll
      for (int mt = 0; mt < 4; ++mt)
        #pragma unroll
        for (int nt = 0; nt < 4; ++nt)
          acc[mt][nt] = __builtin_amdgcn_mfma_f32_16x16x32_bf16(af[mt], bf[nt], acc[mt][nt], 0, 0, 0);
    }
  }
  #pragma unroll
  for (int mt = 0; mt < 4; ++mt) {
    int mrow = M0 + mrow0 + mt*16 + quad*4;
    #pragma unroll
    for (int nt = 0; nt < 4; ++nt) {
      int col = N0 + ncol0 + nt*16 + row16;
      #pragma unroll
      for (int r = 0; r < 4; ++r)
        atomicAdd(&z0[(size_t)(img_base + mrow + r)*256 + col], acc[mt][nt][r]);
    }
  }
}

// ---------------- post ----------------
__global__ void __launch_bounds__(256) k_post(const float* __restrict__ z0,
    const float* __restrict__ enc_b, const float* __restrict__ nfw,
    const float* __restrict__ nfb, const float* __restrict__ protos,
    const float* __restrict__ ws, const float* __restrict__ clf_b,
    float* __restrict__ out) {
  __shared__ float z0s[256], zs[256], wj[256], bls[256];
  __shared__ float red[4];
  int b = blockIdx.x, t = threadIdx.x;
  z0s[t] = z0[(size_t)b*256 + t] + enc_b[t];
  __syncthreads();
  float zv = nfb[t];
  for (int e = 0; e < 256; ++e) zv += z0s[e]*nfw[e*256 + t];
  zs[t] = zv;
  float z2 = block_sum(zv*zv, red);
  const float* pT = ws + OFF_PT;
  const float* gT = ws + OFF_GT;
  float dp = 0.f, dg = 0.f;
  for (int d = 0; d < 256; ++d) {
    float zd = zs[d];
    dp += zd*pT[d*256 + t];
    dg += zd*gT[d*256 + t];
  }
  float d2p = z2 + ws[OFF_PN2 + t] - 2.f*dp;
  float d2g = z2 + ws[OFF_GN2 + t] - 2.f*dg;
  float dtot = sqrtf(fmaxf(d2p, 0.f)) + sqrtf(fmaxf(d2g, 0.f));
  float l = -dtot / ws[OFF_TEMP];
  float m  = block_max(l, red);
  float e  = expf(l - m);
  float E  = block_sum(e, red);
  float w1 = (e/E)*ws[OFF_GATE + t];
  float W  = block_sum(w1, red);
  float wv = w1/(W + 1e-8f);
  wj[t] = wv;
  __syncthreads();
  float bl = 0.f;
  for (int j = 0; j < 256; ++j) bl += wj[j]*protos[j*256 + t];
  bls[t] = bl;
  __syncthreads();
  if (t < 10) {
    float s = clf_b[t];
    for (int d = 0; d < 256; ++d) s += bls[d]*ws[OFF_WEFF + d*10 + t];
    out[(size_t)b*10 + t] = s;
  }
}

extern "C" void kernel_launch(void* const* d_in, const int* in_sizes, int n_in,
                              void* d_out, int out_size, void* d_ws, size_t ws_size,
                              hipStream_t stream) {
  (void)in_sizes; (void)n_in; (void)out_size; (void)ws_size;
  const float* x      = (const float*)d_in[0];
  const float* c1w    = (const float*)d_in[2];
  const float* c1b    = (const float*)d_in[3];
  const float* c2w    = (const float*)d_in[4];
  const float* c2b    = (const float*)d_in[5];
  const float* c3w    = (const float*)d_in[6];
  const float* c3b    = (const float*)d_in[7];
  const float* c4w    = (const float*)d_in[8];
  const float* c4b    = (const float*)d_in[9];
  const float* encw   = (const float*)d_in[10];
  const float* encb   = (const float*)d_in[11];
  // d_in[12..17] dead: softmax over a single node == 1 exactly
  const float* clfw   = (const float*)d_in[18];
  const float* clfb   = (const float*)d_in[19];
  const float* nfw    = (const float*)d_in[20];
  const float* nfb    = (const float*)d_in[21];
  const float* protos = (const float*)d_in[22];
  const float* gridp  = (const float*)d_in[23];
  const float* traw   = (const float*)d_in[24];
  const float* gatel  = (const float*)d_in[25];

  float*  ws  = (float*)d_ws;
  ushort* w2t = (ushort*)((char*)d_ws + OFF_W2T_BYTES);
  ushort* w3t = (ushort*)((char*)d_ws + OFF_W3T_BYTES);
  ushort* w4t = (ushort*)((char*)d_ws + OFF_W4T_BYTES);
  ushort* ewt = (ushort*)((char*)d_ws + OFF_EWT_BYTES);
  ushort* h4c = (ushort*)((char*)d_ws + OFF_A_BYTES);
  ushort* h2c = (ushort*)((char*)d_ws + OFF_B_BYTES);
  float*  z0  = (float*) ((char*)d_ws + OFF_Z0_BYTES);
  float*  out = (float*)d_out;

  hipLaunchKernelGGL(k_setup, dim3(256),  dim3(TPB), 0, stream, protos, gridp, gatel, traw, clfw, ws, z0);
  hipLaunchKernelGGL(k_prep,  dim3(1152), dim3(TPB), 0, stream, c2w, c3w, c4w, w2t, w3t, w4t);
  hipLaunchKernelGGL(k_trans, dim3(256, 4), dim3(TPB), 0, stream, encw, ewt);
  hipLaunchKernelGGL(k_conv12, dim3(4096), dim3(TPB), 0, stream, x, c1w, c1b, w2t, c2b, h2c);
  for (int c = 0; c < 2; ++c) {
    hipLaunchKernelGGL(k_conv34, dim3(2048), dim3(TPB), 0, stream,
                       h2c, c3b, c4b, w3t, w4t, h4c, c*2048);
    hipLaunchKernelGGL(k_enc, dim3(256), dim3(TPB), 0, stream, h4c, ewt, z0, c*2048);
  }
  hipLaunchKernelGGL(k_post, dim3(4096), dim3(TPB), 0, stream, z0, encb, nfw, nfb, protos, ws, clfb, out);
}